// Round 1
// baseline (84.004 us; speedup 1.0000x reference)
//
#include <hip/hip_runtime.h>

// TripletMarginLoss, N=512 anchors, D=128, labels in [0,64).
// loss = sum_{valid (i,j,k)} relu(dm[i,j]-dm[i,k]+1) / (count(> eps) + eps)
// valid(i,j,k) <=> j!=i && lab[j]==lab[i] && lab[k]!=lab[i]
//   (k!=i and k!=j are implied by lab[k]!=lab[i]==lab[j])
//
// Single-launch design: no d_ws usage at all (the harness re-poisons the
// 256 MiB workspace with a ~40 us fill; staying out of ws is the hedge),
// no second reduce kernel. Cross-block combine via device-scope float
// atomics on __device__ globals + ticket; the last block finalizes and
// restores the globals to zero so every launch (and graph replay) starts
// from the same state.

#define TN 512
#define TD 128
#define TMARGIN 1.0f
#define TEPS 1e-8f

__device__ float        g_sum    = 0.f;
__device__ float        g_cnt    = 0.f;
__device__ unsigned int g_ticket = 0u;

__global__ __launch_bounds__(256) void triplet_fused_kernel(
    const float* __restrict__ emb,
    const int* __restrict__ labels,
    float* __restrict__ out)
{
    __shared__ float d[TN];       // dm row for this anchor
    __shared__ float pv[TN];      // positives: d[j] + margin
    __shared__ int   lab[TN];     // labels staged in LDS
    __shared__ int   npos;
    __shared__ float red_s[4], red_c[4];

    const int i = blockIdx.x;
    const int t = threadIdx.x;

    // stage labels (only consumer is after the first barrier)
    for (int j = t; j < TN; j += 256) lab[j] = labels[j];
    if (t == 0) npos = 0;

    // anchor embedding straight to registers: lane (q,sub) needs chunks
    // c = sub + 4*m. Addresses repeat across quads -> broadcast from cache.
    const int q   = t >> 2;
    const int sub = t & 3;
    const float4* ai4 = (const float4*)(emb + i * TD);
    float4 w[8];
#pragma unroll
    for (int m = 0; m < 8; ++m) w[m] = ai4[sub + 4 * m];

    // dm row, coalesced: 4 lanes per row. Quad q handles row p*64+q;
    // lane sub reads float4 chunks sub, sub+4, ..., sub+28.
#pragma unroll
    for (int p = 0; p < 8; ++p) {
        const int row = p * 64 + q;
        const float4* rp = (const float4*)(emb + row * TD);
        float acc = 0.f;
#pragma unroll
        for (int m = 0; m < 8; ++m) {
            float4 v = rp[sub + 4 * m];
            acc += v.x * w[m].x + v.y * w[m].y + v.z * w[m].z + v.w * w[m].w;
        }
        acc += __shfl_xor(acc, 1);
        acc += __shfl_xor(acc, 2);
        if (sub == 0) d[row] = acc;
    }
    __syncthreads();   // d[], lab[], npos=0 all visible

    // collect positives for this anchor
    const int lab_i = lab[i];
    for (int j = t; j < TN; j += 256) {
        if (j != i && lab[j] == lab_i) {
            int idx = atomicAdd(&npos, 1);
            pv[idx] = d[j] + TMARGIN;
        }
    }
    __syncthreads();

    const int np = npos;
    float lsum = 0.f, lcnt = 0.f;
    // threads sweep negatives; inner loop over the few positives
    for (int k = t; k < TN; k += 256) {
        if (lab[k] != lab_i) {
            const float dn = d[k];
            for (int p = 0; p < np; ++p) {
                const float v = pv[p] - dn;
                if (v > 0.f)   lsum += v;
                if (v > TEPS)  lcnt += 1.f;
            }
        }
    }

    // wave(64) shuffle reduction, then cross-wave via LDS
#pragma unroll
    for (int off = 32; off > 0; off >>= 1) {
        lsum += __shfl_down(lsum, off);
        lcnt += __shfl_down(lcnt, off);
    }
    const int wave = t >> 6;
    if ((t & 63) == 0) { red_s[wave] = lsum; red_c[wave] = lcnt; }
    __syncthreads();

    if (t == 0) {
        const float bs = red_s[0] + red_s[1] + red_s[2] + red_s[3];
        const float bc = red_c[0] + red_c[1] + red_c[2] + red_c[3];
        // device-scope atomics (coherent across XCDs)
        atomicAdd(&g_sum, bs);
        atomicAdd(&g_cnt, bc);
        __threadfence();
        const unsigned int old = atomicAdd(&g_ticket, 1u);
        if (old == (unsigned int)(gridDim.x - 1)) {
            // last block: every other block's adds precede its ticket
            __threadfence();
            const float s = atomicAdd(&g_sum, 0.f);   // coherent read
            const float c = atomicAdd(&g_cnt, 0.f);
            out[0] = s / (c + TEPS);
            // restore the all-zeros invariant for the next launch/replay
            atomicExch(&g_sum, 0.f);
            atomicExch(&g_cnt, 0.f);
            __threadfence();
            atomicExch(&g_ticket, 0u);
        }
    }
}

extern "C" void kernel_launch(void* const* d_in, const int* in_sizes, int n_in,
                              void* d_out, int out_size, void* d_ws, size_t ws_size,
                              hipStream_t stream) {
    const float* emb  = (const float*)d_in[0];
    const int* labels = (const int*)d_in[1];   // harness delivers integer inputs as int32
    float* out = (float*)d_out;
    (void)d_ws; (void)ws_size;                 // deliberately untouched

    triplet_fused_kernel<<<TN, 256, 0, stream>>>(emb, labels, out);
}

// Round 2
// 67.570 us; speedup vs baseline: 1.2432x; 1.2432x over previous
//
#include <hip/hip_runtime.h>

// TripletMarginLoss, N=512 anchors, D=128, labels in [0,64).
// loss = sum_{valid (i,j,k)} relu(dm[i,j]-dm[i,k]+1) / (count(> eps) + eps)
// valid(i,j,k) <=> j!=i && lab[j]==lab[i] && lab[k]!=lab[i]
//
// Round-2 structure: two dispatches (stream order IS the grid barrier —
// round 1 proved per-block device-scope fences/atomics cost ~25-30 us on
// non-coherent XCD L2s; never again). ws poison is unconditional (~40 us
// fixed tax), so ws is free to use.
//
// Kernel1: 256 blocks x 2 anchors. Each emb float4 read from L2 feeds TWO
// register-held anchor fragments -> L2 traffic halves (134 MB -> 67 MB).
// Both anchors' partials collapse into one {sum,count} pair per block.

#define TN 512
#define TD 128
#define TMARGIN 1.0f
#define TEPS 1e-8f

// Kernel 1: block b handles anchors i0=2b, i1=2b+1.
__global__ __launch_bounds__(256) void triplet_partial_kernel(
    const float* __restrict__ emb,
    const int* __restrict__ labels,
    float* __restrict__ ws)      // ws[2*b]=sum_b, ws[2*b+1]=count_b
{
    __shared__ float d0[TN], d1[TN];    // dm rows for the two anchors
    __shared__ float pv0[TN], pv1[TN];  // positives: d[j] + margin
    __shared__ int   lab[TN];
    __shared__ int   npos0, npos1;
    __shared__ float red_s[4], red_c[4];

    const int b  = blockIdx.x;
    const int i0 = 2 * b;
    const int i1 = 2 * b + 1;
    const int t  = threadIdx.x;

    for (int j = t; j < TN; j += 256) lab[j] = labels[j];
    if (t == 0) { npos0 = 0; npos1 = 0; }

    // Anchor fragments in registers. Lane (q,sub) needs chunks sub+4m;
    // addresses repeat across quads -> broadcast from L1.
    const int q   = t >> 2;
    const int sub = t & 3;
    const float4* a0 = (const float4*)(emb + i0 * TD);
    const float4* a1 = (const float4*)(emb + i1 * TD);
    float4 w0[8], w1[8];
#pragma unroll
    for (int m = 0; m < 8; ++m) { w0[m] = a0[sub + 4 * m]; w1[m] = a1[sub + 4 * m]; }

    // dm rows, coalesced: quad q handles row p*64+q; lane sub reads float4
    // chunks sub, sub+4, ..., sub+28. Each load feeds 2 dot products.
#pragma unroll
    for (int p = 0; p < 8; ++p) {
        const int row = p * 64 + q;
        const float4* rp = (const float4*)(emb + row * TD);
        float acc0 = 0.f, acc1 = 0.f;
#pragma unroll
        for (int m = 0; m < 8; ++m) {
            float4 v = rp[sub + 4 * m];
            acc0 += v.x * w0[m].x + v.y * w0[m].y + v.z * w0[m].z + v.w * w0[m].w;
            acc1 += v.x * w1[m].x + v.y * w1[m].y + v.z * w1[m].z + v.w * w1[m].w;
        }
        acc0 += __shfl_xor(acc0, 1);
        acc0 += __shfl_xor(acc0, 2);
        acc1 += __shfl_xor(acc1, 1);
        acc1 += __shfl_xor(acc1, 2);
        if (sub == 0) { d0[row] = acc0; d1[row] = acc1; }
    }
    __syncthreads();   // d0/d1, lab, npos visible

    // collect positives for both anchors in one pass
    const int li0 = lab[i0], li1 = lab[i1];
    for (int j = t; j < TN; j += 256) {
        const int lj = lab[j];
        if (j != i0 && lj == li0) pv0[atomicAdd(&npos0, 1)] = d0[j] + TMARGIN;
        if (j != i1 && lj == li1) pv1[atomicAdd(&npos1, 1)] = d1[j] + TMARGIN;
    }
    __syncthreads();

    const int np0 = npos0, np1 = npos1;
    float lsum = 0.f, lcnt = 0.f;
    for (int k = t; k < TN; k += 256) {
        const int lk = lab[k];
        if (lk != li0) {
            const float dn = d0[k];
            for (int p = 0; p < np0; ++p) {
                const float v = pv0[p] - dn;
                if (v > 0.f)   lsum += v;
                if (v > TEPS)  lcnt += 1.f;
            }
        }
        if (lk != li1) {
            const float dn = d1[k];
            for (int p = 0; p < np1; ++p) {
                const float v = pv1[p] - dn;
                if (v > 0.f)   lsum += v;
                if (v > TEPS)  lcnt += 1.f;
            }
        }
    }

    // wave(64) shuffle reduction, then cross-wave via LDS
#pragma unroll
    for (int off = 32; off > 0; off >>= 1) {
        lsum += __shfl_down(lsum, off);
        lcnt += __shfl_down(lcnt, off);
    }
    const int wave = t >> 6;
    if ((t & 63) == 0) { red_s[wave] = lsum; red_c[wave] = lcnt; }
    __syncthreads();

    if (t == 0) {
        ws[2 * b]     = red_s[0] + red_s[1] + red_s[2] + red_s[3];
        ws[2 * b + 1] = red_c[0] + red_c[1] + red_c[2] + red_c[3];
    }
}

// Kernel 2: one wave reduces 256 {sum,count} pairs and finalizes.
// 64 threads, no LDS, no barrier.
__global__ __launch_bounds__(64) void triplet_reduce_kernel(
    const float* __restrict__ ws,
    float* __restrict__ out)
{
    const int t = threadIdx.x;
    float lsum = 0.f, lcnt = 0.f;
#pragma unroll
    for (int r = 0; r < 4; ++r) {
        const float2 p = ((const float2*)ws)[t + 64 * r];
        lsum += p.x;
        lcnt += p.y;
    }
#pragma unroll
    for (int off = 32; off > 0; off >>= 1) {
        lsum += __shfl_down(lsum, off);
        lcnt += __shfl_down(lcnt, off);
    }
    if (t == 0) out[0] = lsum / (lcnt + TEPS);
}

extern "C" void kernel_launch(void* const* d_in, const int* in_sizes, int n_in,
                              void* d_out, int out_size, void* d_ws, size_t ws_size,
                              hipStream_t stream) {
    const float* emb  = (const float*)d_in[0];
    const int* labels = (const int*)d_in[1];   // harness delivers integer inputs as int32
    float* out = (float*)d_out;
    float* ws  = (float*)d_ws;

    triplet_partial_kernel<<<256, 256, 0, stream>>>(emb, labels, ws);
    triplet_reduce_kernel<<<1, 64, 0, stream>>>(ws, out);
}

// Round 3
// 63.155 us; speedup vs baseline: 1.3301x; 1.0699x over previous
//
#include <hip/hip_runtime.h>

// TripletMarginLoss, N=512 anchors, D=128, labels in [0,64).
// loss = sum_{valid (i,j,k)} relu(dm[i,j]-dm[i,k]+1) / (count(> eps) + eps)
// valid(i,j,k) <=> j!=i && lab[j]==lab[i] && lab[k]!=lab[i]
//
// Round-3 structure: two dispatches (stream order is the grid barrier;
// round 1 proved device-scope atomic/fence tails cost 25+ us). The 256 MiB
// ws poison (~40 us) is an unconditional harness tax.
//
// k1: 256 blocks x 512 threads, 2 anchors per block.
//   - 8 waves/CU (round-0 latency hiding) AND 2-anchor register reuse
//     (round-2 traffic). Round 2 showed k1 is LATENCY-bound: 256x256
//     (4 waves/CU) regressed vs 512 blocks (8 waves/CU) despite half the
//     L2 traffic. This config restores waves and halves per-thread load
//     chains (32 float4 loads/thread vs round-0's 64).

#define TN 512
#define TD 128
#define TMARGIN 1.0f
#define TEPS 1e-8f

// Kernel 1: block b handles anchors i0=2b, i1=2b+1. 512 threads.
__global__ __launch_bounds__(512) void triplet_partial_kernel(
    const float* __restrict__ emb,
    const int* __restrict__ labels,
    float* __restrict__ ws)      // ws[2*b]=sum_b, ws[2*b+1]=count_b
{
    __shared__ float d0[TN], d1[TN];    // dm rows for the two anchors
    __shared__ float pv0[TN], pv1[TN];  // positives: d[j] + margin
    __shared__ int   lab[TN];
    __shared__ int   npos0, npos1;
    __shared__ float red_s[8], red_c[8];

    const int b  = blockIdx.x;
    const int i0 = 2 * b;
    const int i1 = 2 * b + 1;
    const int t  = threadIdx.x;          // [0,512)

    lab[t] = labels[t];                  // one label per thread
    if (t == 0) { npos0 = 0; npos1 = 0; }

    // Anchor fragments in registers. Lane (q,sub) needs chunks sub+4m;
    // addresses repeat across quads -> broadcast from L1.
    const int q   = t >> 2;              // [0,128): row within pass
    const int sub = t & 3;
    const float4* a0 = (const float4*)(emb + i0 * TD);
    const float4* a1 = (const float4*)(emb + i1 * TD);
    float4 w0[8], w1[8];
#pragma unroll
    for (int m = 0; m < 8; ++m) { w0[m] = a0[sub + 4 * m]; w1[m] = a1[sub + 4 * m]; }

    // dm rows: 4 passes x 128 rows. Quad q handles row p*128+q; lane sub
    // reads float4 chunks sub, sub+4, ..., sub+28 (64 B contiguous per
    // quad per m). Each load feeds both anchors' dot products.
#pragma unroll
    for (int p = 0; p < 4; ++p) {
        const int row = p * 128 + q;
        const float4* rp = (const float4*)(emb + row * TD);
        float acc0 = 0.f, acc1 = 0.f;
#pragma unroll
        for (int m = 0; m < 8; ++m) {
            float4 v = rp[sub + 4 * m];
            acc0 += v.x * w0[m].x + v.y * w0[m].y + v.z * w0[m].z + v.w * w0[m].w;
            acc1 += v.x * w1[m].x + v.y * w1[m].y + v.z * w1[m].z + v.w * w1[m].w;
        }
        acc0 += __shfl_xor(acc0, 1);
        acc0 += __shfl_xor(acc0, 2);
        acc1 += __shfl_xor(acc1, 1);
        acc1 += __shfl_xor(acc1, 2);
        if (sub == 0) { d0[row] = acc0; d1[row] = acc1; }
    }
    __syncthreads();   // d0/d1, lab, npos visible

    // collect positives for both anchors: one j per thread
    const int li0 = lab[i0], li1 = lab[i1];
    {
        const int j  = t;
        const int lj = lab[j];
        if (j != i0 && lj == li0) pv0[atomicAdd(&npos0, 1)] = d0[j] + TMARGIN;
        if (j != i1 && lj == li1) pv1[atomicAdd(&npos1, 1)] = d1[j] + TMARGIN;
    }
    __syncthreads();

    const int np0 = npos0, np1 = npos1;
    float lsum = 0.f, lcnt = 0.f;
    {
        const int k  = t;                // one negative candidate per thread
        const int lk = lab[k];
        if (lk != li0) {
            const float dn = d0[k];
            for (int p = 0; p < np0; ++p) {
                const float v = pv0[p] - dn;
                if (v > 0.f)   lsum += v;
                if (v > TEPS)  lcnt += 1.f;
            }
        }
        if (lk != li1) {
            const float dn = d1[k];
            for (int p = 0; p < np1; ++p) {
                const float v = pv1[p] - dn;
                if (v > 0.f)   lsum += v;
                if (v > TEPS)  lcnt += 1.f;
            }
        }
    }

    // wave(64) shuffle reduction, then cross-wave via LDS
#pragma unroll
    for (int off = 32; off > 0; off >>= 1) {
        lsum += __shfl_down(lsum, off);
        lcnt += __shfl_down(lcnt, off);
    }
    const int wave = t >> 6;             // [0,8)
    if ((t & 63) == 0) { red_s[wave] = lsum; red_c[wave] = lcnt; }
    __syncthreads();

    if (t == 0) {
        float s = 0.f, c = 0.f;
#pragma unroll
        for (int wv = 0; wv < 8; ++wv) { s += red_s[wv]; c += red_c[wv]; }
        ws[2 * b]     = s;
        ws[2 * b + 1] = c;
    }
}

// Kernel 2: one wave reduces 256 {sum,count} pairs and finalizes.
__global__ __launch_bounds__(64) void triplet_reduce_kernel(
    const float* __restrict__ ws,
    float* __restrict__ out)
{
    const int t = threadIdx.x;
    float lsum = 0.f, lcnt = 0.f;
#pragma unroll
    for (int r = 0; r < 4; ++r) {
        const float2 p = ((const float2*)ws)[t + 64 * r];
        lsum += p.x;
        lcnt += p.y;
    }
#pragma unroll
    for (int off = 32; off > 0; off >>= 1) {
        lsum += __shfl_down(lsum, off);
        lcnt += __shfl_down(lcnt, off);
    }
    if (t == 0) out[0] = lsum / (lcnt + TEPS);
}

extern "C" void kernel_launch(void* const* d_in, const int* in_sizes, int n_in,
                              void* d_out, int out_size, void* d_ws, size_t ws_size,
                              hipStream_t stream) {
    const float* emb  = (const float*)d_in[0];
    const int* labels = (const int*)d_in[1];   // harness delivers integer inputs as int32
    float* out = (float*)d_out;
    float* ws  = (float*)d_ws;

    triplet_partial_kernel<<<256, 512, 0, stream>>>(emb, labels, ws);
    triplet_reduce_kernel<<<1, 64, 0, stream>>>(ws, out);
}

// Round 4
// 60.365 us; speedup vs baseline: 1.3916x; 1.0462x over previous
//
#include <hip/hip_runtime.h>

// TripletMarginLoss, N=512 anchors, D=128, labels in [0,64).
// loss = sum_{valid (i,j,k)} relu(dm[i,j]-dm[i,k]+1) / (count(> eps) + eps)
// valid(i,j,k) <=> j!=i && lab[j]==lab[i] && lab[k]!=lab[i]
//
// Structure (locked in by rounds 0-3):
//   - Two dispatches; stream order is the grid barrier. R1 proved per-block
//     device-scope atomics/fences cost 25+ us on non-coherent XCD L2s.
//   - The 256 MiB ws poison (~39.5 us, 85% HBM-write peak) is an
//     unconditional harness tax; ws is free to use.
//   - k1 is LATENCY-bound, not traffic-bound: R2 (1 wave/SIMD) lost 4.4 us;
//     R0 (134 MB) == R3 (67 MB) at 2 waves/SIMD.
//
// Round-4 single variable: 256 blocks x 1024 threads (16 waves/CU,
// 4 waves/SIMD) with 8 lanes/row -> per-thread load chain 40 -> 24 and the
// hinge sweep split across anchor halves. If this doesn't move dur_us, k1
// is at its floor and the measurement is fill + harness resets => roofline.

#define TN 512
#define TD 128
#define TMARGIN 1.0f
#define TEPS 1e-8f

// Kernel 1: block b handles anchors i0=2b, i1=2b+1. 1024 threads.
__global__ __launch_bounds__(1024) void triplet_partial_kernel(
    const float* __restrict__ emb,
    const int* __restrict__ labels,
    float* __restrict__ ws)      // ws[2*b]=sum_b, ws[2*b+1]=count_b
{
    __shared__ float d0[TN], d1[TN];    // dm rows for the two anchors
    __shared__ float pv0[TN], pv1[TN];  // positives: d[j] + margin
    __shared__ int   lab[TN];
    __shared__ int   npos0, npos1;
    __shared__ float red_s[16], red_c[16];

    const int b  = blockIdx.x;
    const int i0 = 2 * b;
    const int i1 = 2 * b + 1;
    const int t  = threadIdx.x;          // [0,1024)

    if (t < TN) lab[t] = labels[t];
    if (t == 0) { npos0 = 0; npos1 = 0; }

    // Anchor fragments in registers. Octet lane (oct,sub): chunks sub+8m,
    // m=0..3. Addresses repeat across octets -> cache broadcast.
    const int oct = t >> 3;              // [0,128): row within pass
    const int sub = t & 7;
    const float4* a0 = (const float4*)(emb + i0 * TD);
    const float4* a1 = (const float4*)(emb + i1 * TD);
    float4 w0[4], w1[4];
#pragma unroll
    for (int m = 0; m < 4; ++m) { w0[m] = a0[sub + 8 * m]; w1[m] = a1[sub + 8 * m]; }

    // dm rows: 4 passes x 128 rows. Octet oct handles row p*128+oct; lane
    // sub reads float4 chunks sub, sub+8, sub+16, sub+24 (128 B contiguous
    // per octet per m). Each load feeds both anchors' dot products.
#pragma unroll
    for (int p = 0; p < 4; ++p) {
        const int row = p * 128 + oct;
        const float4* rp = (const float4*)(emb + row * TD);
        float acc0 = 0.f, acc1 = 0.f;
#pragma unroll
        for (int m = 0; m < 4; ++m) {
            float4 v = rp[sub + 8 * m];
            acc0 += v.x * w0[m].x + v.y * w0[m].y + v.z * w0[m].z + v.w * w0[m].w;
            acc1 += v.x * w1[m].x + v.y * w1[m].y + v.z * w1[m].z + v.w * w1[m].w;
        }
        acc0 += __shfl_xor(acc0, 1);
        acc0 += __shfl_xor(acc0, 2);
        acc0 += __shfl_xor(acc0, 4);
        acc1 += __shfl_xor(acc1, 1);
        acc1 += __shfl_xor(acc1, 2);
        acc1 += __shfl_xor(acc1, 4);
        if (sub == 0) { d0[row] = acc0; d1[row] = acc1; }
    }
    __syncthreads();   // d0/d1, lab, npos visible

    // collect positives for both anchors: one j per thread (first 512)
    const int li0 = lab[i0], li1 = lab[i1];
    if (t < TN) {
        const int lj = lab[t];
        if (t != i0 && lj == li0) pv0[atomicAdd(&npos0, 1)] = d0[t] + TMARGIN;
        if (t != i1 && lj == li1) pv1[atomicAdd(&npos1, 1)] = d1[t] + TMARGIN;
    }
    __syncthreads();

    const int np0 = npos0, np1 = npos1;
    float lsum = 0.f, lcnt = 0.f;
    {
        // threads 0-511: anchor 0's negatives; 512-1023: anchor 1's.
        // Wave-uniform split (t<512 at wave granularity).
        const int k  = t & (TN - 1);
        const int lk = lab[k];
        if (t < TN) {
            if (lk != li0) {
                const float dn = d0[k];
                for (int p = 0; p < np0; ++p) {
                    const float v = pv0[p] - dn;
                    if (v > 0.f)   lsum += v;
                    if (v > TEPS)  lcnt += 1.f;
                }
            }
        } else {
            if (lk != li1) {
                const float dn = d1[k];
                for (int p = 0; p < np1; ++p) {
                    const float v = pv1[p] - dn;
                    if (v > 0.f)   lsum += v;
                    if (v > TEPS)  lcnt += 1.f;
                }
            }
        }
    }

    // wave(64) shuffle reduction, then cross-wave via LDS
#pragma unroll
    for (int off = 32; off > 0; off >>= 1) {
        lsum += __shfl_down(lsum, off);
        lcnt += __shfl_down(lcnt, off);
    }
    const int wave = t >> 6;             // [0,16)
    if ((t & 63) == 0) { red_s[wave] = lsum; red_c[wave] = lcnt; }
    __syncthreads();

    if (t == 0) {
        float s = 0.f, c = 0.f;
#pragma unroll
        for (int wv = 0; wv < 16; ++wv) { s += red_s[wv]; c += red_c[wv]; }
        ws[2 * b]     = s;
        ws[2 * b + 1] = c;
    }
}

// Kernel 2: one wave reduces 256 {sum,count} pairs and finalizes.
__global__ __launch_bounds__(64) void triplet_reduce_kernel(
    const float* __restrict__ ws,
    float* __restrict__ out)
{
    const int t = threadIdx.x;
    float lsum = 0.f, lcnt = 0.f;
#pragma unroll
    for (int r = 0; r < 4; ++r) {
        const float2 p = ((const float2*)ws)[t + 64 * r];
        lsum += p.x;
        lcnt += p.y;
    }
#pragma unroll
    for (int off = 32; off > 0; off >>= 1) {
        lsum += __shfl_down(lsum, off);
        lcnt += __shfl_down(lcnt, off);
    }
    if (t == 0) out[0] = lsum / (lcnt + TEPS);
}

extern "C" void kernel_launch(void* const* d_in, const int* in_sizes, int n_in,
                              void* d_out, int out_size, void* d_ws, size_t ws_size,
                              hipStream_t stream) {
    const float* emb  = (const float*)d_in[0];
    const int* labels = (const int*)d_in[1];   // harness delivers integer inputs as int32
    float* out = (float*)d_out;
    float* ws  = (float*)d_ws;

    triplet_partial_kernel<<<256, 1024, 0, stream>>>(emb, labels, ws);
    triplet_reduce_kernel<<<1, 64, 0, stream>>>(ws, out);
}